// Round 2
// baseline (4167.551 us; speedup 1.0000x reference)
//
#include <hip/hip_runtime.h>

// GRU fused recurrent kernel, fp32, packed-pair register-broadcast version.
// B=256, S=2048, I=64, H=128. One block per batch element (256 blocks).
// 192 threads = 3 waves, one per SIMD (balanced; old 384-thread version put
// 6 waves on 4 SIMDs -> (2,2,1,1) imbalance gated every barrier interval).
//
// Each lane owns TWO gate columns (cA, cB) with weights held as float2 in
// VGPRs, so one v_readlane broadcast feeds one v_pk_fma_f32 covering both
// columns: per-k VALU cost per 128 columns drops ~2x vs the 1-col version.
//   wave 0: (r_l,     n_l)      cols (l,     256+l)
//   wave 1: (r_{64+l},n_{64+l}) cols (64+l,  320+l)
//   wave 2: (z_l,     z_{64+l}) cols (128+l, 192+l)
// Pairing r with n means n = tanh(xn + r*hn) uses the lane's OWN r register:
// r never touches LDS and the old r-barrier dependency is gone. Only z
// crosses the (single) producer barrier.
//
// NOTE (R2 resubmit): R1 bench died with "container failed twice" (infra),
// no compile/verify verdict. Design unchanged; minor address hoisting only.

#define S_LEN 2048

typedef float f32x2 __attribute__((ext_vector_type(2)));

__device__ __forceinline__ f32x2 fma2(float b, f32x2 w, f32x2 acc) {
#if __has_builtin(__builtin_elementwise_fma)
    f32x2 bb = {b, b};
    return __builtin_elementwise_fma(bb, w, acc);   // -> v_pk_fma_f32
#else
    acc.x = fmaf(b, w.x, acc.x);
    acc.y = fmaf(b, w.y, acc.y);
    return acc;
#endif
}

__device__ __forceinline__ float sigm(float x) {
    x = fminf(fmaxf(x, -30.f), 30.f);
    return 1.0f / (1.0f + __expf(-x));
}
__device__ __forceinline__ float tanh_fast(float x) {
    x = fminf(fmaxf(x, -15.f), 15.f);
    float e = __expf(2.0f * x);
    return (e - 1.0f) / (e + 1.0f);
}

__global__ __launch_bounds__(192, 1) void gru_pk_kernel(
    const float* __restrict__ x,     // (256, 2048, 64)
    const float* __restrict__ Win,   // (64, 384)
    const float* __restrict__ Wh,    // (128, 384)
    const float* __restrict__ bias,  // (768,)
    float* __restrict__ out)         // (256,2048,128) then (256,128)
{
    const int b = blockIdx.x;
    const int j = threadIdx.x;       // 0..191
    const int w = j >> 6;            // wave id 0..2
    const int l = j & 63;            // lane

    __shared__ float h_buf[2][128];  // ping-pong hidden state
    __shared__ float z_buf[2][128];  // ping-pong z gate
    volatile float* hb = &h_buf[0][0];
    volatile float* zb = &z_buf[0][0];

    int cA, cB;
    if (w == 0)      { cA = l;       cB = 256 + l; }
    else if (w == 1) { cA = 64 + l;  cB = 320 + l; }
    else             { cA = 128 + l; cB = 192 + l; }

    // Per-thread weight column PAIR in registers (~384 VGPRs of weights).
    // Loops MUST be fully unrolled: any dynamic index demotes to scratch.
    f32x2 wx2[64];
    f32x2 wh2[128];
#pragma unroll
    for (int k = 0; k < 64; ++k) {
        wx2[k].x = Win[k * 384 + cA];    // coalesced 256B runs per wave
        wx2[k].y = Win[k * 384 + cB];
    }
#pragma unroll
    for (int k = 0; k < 128; ++k) {
        wh2[k].x = Wh[k * 384 + cA];
        wh2[k].y = Wh[k * 384 + cB];
    }
    const f32x2 bx2 = { bias[cA],       bias[cB] };
    const f32x2 bh2 = { bias[384 + cA], bias[384 + cB] };

    if (j < 128) h_buf[0][j] = 0.0f;

    const float* xb   = x   + (size_t)b * S_LEN * 64;
    float*       outb = out + (size_t)b * S_LEN * 128;

    float vx = xb[l];      // x[b][0][lane]
    __syncthreads();       // h init visible

    for (int t = 0; t < S_LEN; ++t) {
        const int p = t & 1;
        volatile float* hb_cur = hb + p * 128;
        volatile float* hb_nxt = hb + (p ^ 1) * 128;
        volatile float* zb_cur = zb + p * 128;

        // h_{t-1}: 2 conflict-free ds_read_b32 per wave (broadcast source)
        float vh0 = hb_cur[l];        // h[l]
        float vh1 = hb_cur[64 + l];   // h[64+l]

        // prefetch next x_t (L2-resident; hidden behind the k-loops)
        const int tn = (t + 1 < S_LEN) ? (t + 1) : t;
        float vxn = xb[tn * 64 + l];

        // x-part: accx2 = b_in[cA,cB] + sum_k x[t][k] * Win[k][cA,cB]
        const int ix = __float_as_int(vx);
        f32x2 ax0 = bx2, ax1 = {0.f, 0.f};
#pragma unroll
        for (int k = 0; k < 64; k += 2) {
            float b0 = __int_as_float(__builtin_amdgcn_readlane(ix, k));
            float b1 = __int_as_float(__builtin_amdgcn_readlane(ix, k + 1));
            ax0 = fma2(b0, wx2[k],     ax0);
            ax1 = fma2(b1, wx2[k + 1], ax1);
        }
        const f32x2 accx = ax0 + ax1;

        // h-part: acch2 = b_h[cA,cB] + sum_k h[k] * Wh[k][cA,cB]
        const int ih0 = __float_as_int(vh0);
        const int ih1 = __float_as_int(vh1);
        f32x2 ah0 = bh2, ah1 = {0.f, 0.f}, ah2 = {0.f, 0.f}, ah3 = {0.f, 0.f};
#pragma unroll
        for (int k = 0; k < 64; k += 2) {
            float b0 = __int_as_float(__builtin_amdgcn_readlane(ih0, k));
            float b1 = __int_as_float(__builtin_amdgcn_readlane(ih0, k + 1));
            float b2 = __int_as_float(__builtin_amdgcn_readlane(ih1, k));
            float b3 = __int_as_float(__builtin_amdgcn_readlane(ih1, k + 1));
            ah0 = fma2(b0, wh2[k],          ah0);
            ah1 = fma2(b1, wh2[k + 1],      ah1);
            ah2 = fma2(b2, wh2[64 + k],     ah2);
            ah3 = fma2(b3, wh2[64 + k + 1], ah3);
        }
        const f32x2 acch = (ah0 + ah1) + (ah2 + ah3);

        float n_val = 0.f;
        if (w < 2) {
            // r uses own register; n needs NO LDS and NO barrier for r.
            float r = sigm(accx.x + acch.x);
            n_val = tanh_fast(fmaf(r, acch.y, accx.y));
        } else {
            zb_cur[l]      = sigm(accx.x + acch.x);   // z[l]
            zb_cur[64 + l] = sigm(accx.y + acch.y);   // z[64+l]
        }
        __syncthreads();   // barrier 1: z visible to r/n-waves
        if (w < 2) {
            const int jj = w ? (64 + l) : l;
            float z  = zb_cur[jj];
            float ho = w ? vh1 : vh0;               // h_{t-1}[jj], own register
            float hn = fmaf(z, ho - n_val, n_val);  // (1-z)*n + z*h
            hb_nxt[jj] = hn;                        // write OTHER buffer
            outb[t * 128 + jj] = hn;                // coalesced
        }
        __syncthreads();   // barrier 2: new h visible for next step
        vx = vxn;
    }

    if (j < 128) {
        // final h is in h_buf[0] (t=2047, p=1, wrote p^1=0)
        out[(size_t)256 * S_LEN * 128 + (size_t)b * 128 + j] = h_buf[0][j];
    }
}

extern "C" void kernel_launch(void* const* d_in, const int* in_sizes, int n_in,
                              void* d_out, int out_size, void* d_ws, size_t ws_size,
                              hipStream_t stream) {
    const float* x    = (const float*)d_in[0];
    const float* Win  = (const float*)d_in[1];
    const float* Wh   = (const float*)d_in[2];
    const float* bias = (const float*)d_in[3];
    float* out = (float*)d_out;

    gru_pk_kernel<<<256, 192, 0, stream>>>(x, Win, Wh, bias, out);
}

// Round 3
// 2208.418 us; speedup vs baseline: 1.8871x; 1.8871x over previous
//
#include <hip/hip_runtime.h>

// GRU fused recurrent kernel, fp32 — "own-the-triple, split-K" version.
// B=256, S=2048, I=64, H=128. One block per batch element (256 blocks).
// 512 threads = 8 waves = 2 waves/SIMD (balanced; R2's 3-wave version was
// 1 wave/SIMD and latency-bound at VALUBusy=43%).
//
// Decomposition: lane owns ALL THREE gate columns of one output index
// j in [0,128): (r_j, z_j, n_j). Gate math is then lane-local — r and z
// never touch LDS (R0/R2 burned a barrier + LDS round trip on them).
// Wave (g,s): g = j-half (j = 64g + lane), s = k-quarter. Each thread
// computes partial dots over 32 h-ks and 16 x-ks; partials are summed via
// one LDS exchange; the two s==0 waves finish gates and write h.
//   per-thread regs: 96 h-weights + 48 x-weights (r,z packed f32x2) ~ 190
//   VGPRs total -> NO AGPR overflow (R2's 384-float weight file spilled to
//   AGPRs, VGPR_Count 208*4=832, with shuttle moves inflating issue).
// Barriers/step: 2. LDS/step: 4 partial-planes + h (single-buffered: reads
// complete before the barrier that precedes the overwrite).

#define S_LEN 2048

typedef float f32x2 __attribute__((ext_vector_type(2)));

__device__ __forceinline__ f32x2 fma2(float b, f32x2 w, f32x2 acc) {
#if __has_builtin(__builtin_elementwise_fma)
    f32x2 bb = {b, b};
    return __builtin_elementwise_fma(bb, w, acc);   // -> v_pk_fma_f32
#else
    acc.x = fmaf(b, w.x, acc.x);
    acc.y = fmaf(b, w.y, acc.y);
    return acc;
#endif
}

__device__ __forceinline__ float sigm(float x) {
    x = fminf(fmaxf(x, -30.f), 30.f);
    return 1.0f / (1.0f + __expf(-x));
}
__device__ __forceinline__ float tanh_fast(float x) {
    x = fminf(fmaxf(x, -15.f), 15.f);
    float e = __expf(2.0f * x);
    return (e - 1.0f) / (e + 1.0f);
}

__global__ __launch_bounds__(512, 1) void gru_splitk_kernel(
    const float* __restrict__ x,     // (256, 2048, 64)
    const float* __restrict__ Win,   // (64, 384)
    const float* __restrict__ Wh,    // (128, 384)
    const float* __restrict__ bias,  // (768,)
    float* __restrict__ out)         // (256,2048,128) then (256,128)
{
    const int b    = blockIdx.x;
    const int tid  = threadIdx.x;    // 0..511
    const int w    = tid >> 6;       // wave 0..7
    const int lane = tid & 63;
    const int s    = w >> 1;         // k-quarter 0..3
    const int g    = w & 1;          // j-half 0..1  (gate waves w=0,1 -> s=0)
    const int j    = 64 * g + lane;  // owned output index 0..127

    __shared__ float h_buf[128];            // hidden state (single buffer OK)
    __shared__ float part[4][4][128];       // [val][s][j]; val: rC,zC,xn,hn

    // ---- weights: k-quarter slice of the 3 owned columns, in registers ----
    f32x2 whrz[32];  float whn[32];         // Wh[32s+i][{j,128+j}], [256+j]
    f32x2 wxrz[16];  float wxn[16];         // Win[16s+i][...]
#pragma unroll
    for (int i = 0; i < 32; ++i) {
        const int k = 32 * s + i;
        whrz[i].x = Wh[k * 384 + j];
        whrz[i].y = Wh[k * 384 + 128 + j];
        whn[i]    = Wh[k * 384 + 256 + j];
    }
#pragma unroll
    for (int i = 0; i < 16; ++i) {
        const int k = 16 * s + i;
        wxrz[i].x = Win[k * 384 + j];
        wxrz[i].y = Win[k * 384 + 128 + j];
        wxn[i]    = Win[k * 384 + 256 + j];
    }
    // biases: r,z can be combined (b_in + b_h); n must stay separate
    // (n = tanh(xn + b_in_n + r*(hn + b_h_n))).
    f32x2 brz;
    brz.x = bias[j]       + bias[384 + j];
    brz.y = bias[128 + j] + bias[512 + j];
    const float bxn = bias[256 + j];
    const float bhn = bias[640 + j];

    if (s == 0) h_buf[j] = 0.0f;

    const float* xb   = x   + (size_t)b * S_LEN * 64;
    float*       outb = out + (size_t)b * S_LEN * 128;

    // x broadcast source: lane holds x[t][16s + (lane&15)]; readlane i<16.
    float vx = xb[16 * s + (lane & 15)];
    __syncthreads();                         // h init visible

    for (int t = 0; t < S_LEN; ++t) {
        // h broadcast source: lane holds h[32s + (lane&31)]; readlane i<32.
        const float vh = h_buf[32 * s + (lane & 31)];
        float h_old = 0.f;
        if (s == 0) h_old = h_buf[j];        // uniform branch per wave

        // prefetch next x_t (L2-resident; hides behind the k-loops)
        const int tn = (t + 1 < S_LEN) ? (t + 1) : t;
        const float vxn = xb[tn * 64 + 16 * s + (lane & 15)];

        // ---- x partial: k in [16s, 16s+16) ----
        const int ix = __float_as_int(vx);
        f32x2 axrz0 = {0.f, 0.f}, axrz1 = {0.f, 0.f};
        float axn0 = 0.f, axn1 = 0.f;
#pragma unroll
        for (int i = 0; i < 16; i += 2) {
            float b0 = __int_as_float(__builtin_amdgcn_readlane(ix, i));
            float b1 = __int_as_float(__builtin_amdgcn_readlane(ix, i + 1));
            axrz0 = fma2(b0, wxrz[i],     axrz0);
            axn0  = fmaf(b0, wxn[i],      axn0);
            axrz1 = fma2(b1, wxrz[i + 1], axrz1);
            axn1  = fmaf(b1, wxn[i + 1],  axn1);
        }

        // ---- h partial: k in [32s, 32s+32) ----
        const int ih = __float_as_int(vh);
        f32x2 ahrz0 = {0.f, 0.f}, ahrz1 = {0.f, 0.f};
        float ahn0 = 0.f, ahn1 = 0.f;
#pragma unroll
        for (int i = 0; i < 32; i += 2) {
            float b0 = __int_as_float(__builtin_amdgcn_readlane(ih, i));
            float b1 = __int_as_float(__builtin_amdgcn_readlane(ih, i + 1));
            ahrz0 = fma2(b0, whrz[i],     ahrz0);
            ahn0  = fmaf(b0, whn[i],      ahn0);
            ahrz1 = fma2(b1, whrz[i + 1], ahrz1);
            ahn1  = fmaf(b1, whn[i + 1],  ahn1);
        }

        // r,z: x-part and h-part combine; n: keep xn / hn separate.
        const f32x2 prz = (ahrz0 + ahrz1) + (axrz0 + axrz1);
        const float pxn = axn0 + axn1;
        const float phn = ahn0 + ahn1;

        if (s != 0) {                        // uniform branch per wave
            part[0][s][j] = prz.x;
            part[1][s][j] = prz.y;
            part[2][s][j] = pxn;
            part[3][s][j] = phn;
        }
        __syncthreads();                     // barrier A: partials visible

        if (s == 0) {
            float sr  = prz.x, sz = prz.y, sxn = pxn, shn = phn;
#pragma unroll
            for (int q = 1; q < 4; ++q) {
                sr  += part[0][q][j];
                sz  += part[1][q][j];
                sxn += part[2][q][j];
                shn += part[3][q][j];
            }
            const float r  = sigm(sr + brz.x);
            const float z  = sigm(sz + brz.y);
            const float n  = tanh_fast(fmaf(r, shn + bhn, sxn + bxn));
            const float hn = fmaf(z, h_old - n, n);   // (1-z)*n + z*h
            h_buf[j] = hn;                   // prior reads drained at barrier A
            outb[t * 128 + j] = hn;          // 2 waves x 256B contiguous
        }
        __syncthreads();                     // barrier B: new h visible
        vx = vxn;
    }

    if (s == 0) {
        out[(size_t)256 * S_LEN * 128 + (size_t)b * 128 + j] = h_buf[j];
    }
}

extern "C" void kernel_launch(void* const* d_in, const int* in_sizes, int n_in,
                              void* d_out, int out_size, void* d_ws, size_t ws_size,
                              hipStream_t stream) {
    const float* x    = (const float*)d_in[0];
    const float* Win  = (const float*)d_in[1];
    const float* Wh   = (const float*)d_in[2];
    const float* bias = (const float*)d_in[3];
    float* out = (float*)d_out;

    gru_splitk_kernel<<<256, 512, 0, stream>>>(x, Win, Wh, bias, out);
}